// Round 7
// baseline (156.393 us; speedup 1.0000x reference)
//
#include <hip/hip_runtime.h>
#include <hip/hip_bf16.h>

#define IN_N   8192
#define OUT_N  8186
#define KS     7

#define WX     112             // output cols per chunk
#define SROW   22              // staged rows per band (16 out + 6 halo)
#define NLDW   11              // float4 load rounds per wave (22*32/64)
#define LSTR   272             // LDS bytes per staged row (128 bf16 + 16B pad)
#define WAVE_LDS (SROW * LSTR) // 5984 B per wave
#define NCHT   74              // total chunks per band (73 full + 1 partial)
#define GCH    73              // guarded chunk index
#define NPANEL 12
#define NGROUP 128             // 4 bands per block -> 512 bands
#define NBLK   (NGROUP * NPANEL) // 1536 = 6 blocks/CU exactly

typedef __bf16 bf16x8 __attribute__((ext_vector_type(8)));
typedef float  f32x4  __attribute__((ext_vector_type(4)));

union BFU { __bf16 h; unsigned short u; };
__device__ __forceinline__ unsigned short f2bf(float f) {
    BFU c; c.h = (__bf16)f; return c.u;
}
union D2 { f32x4 v; double d[2]; };

template<bool G>
struct WavePipe {
    const float* X; float* out;
    char* sb;
    int y0;
    int lo, hi, ls5, l31;
    float bv;
    bf16x8 bfrag[KS];
    float4 ld[NLDW];

    __device__ __forceinline__ void load_chunk(int c) {
        const int xb = c * WX;
        if constexpr (!G) {
            const float* gb = X + (size_t)(y0 + ls5) * IN_N + xb + l31 * 4;
            #pragma unroll
            for (int k = 0; k < NLDW; ++k)
                ld[k] = *(const float4*)(gb + (size_t)(2 * k) * IN_N);
        } else {
            #pragma unroll
            for (int k = 0; k < NLDW; ++k) {
                const int r  = min(y0 + ls5 + 2 * k, IN_N - 1);
                const int cc = min(xb + l31 * 4, IN_N - 4);  // clamped junk only feeds discarded outputs
                ld[k] = *(const float4*)(X + (size_t)r * IN_N + cc);
            }
        }
    }

    __device__ __forceinline__ void write_chunk() {
        char* lb = sb + ls5 * LSTR + l31 * 8;
        #pragma unroll
        for (int k = 0; k < NLDW; ++k) {
            ushort4 h;
            h.x = f2bf(ld[k].x); h.y = f2bf(ld[k].y);
            h.z = f2bf(ld[k].z); h.w = f2bf(ld[k].w);
            *(ushort4*)(lb + k * 544) = h;   // 544 = 2*LSTR
        }
    }

    __device__ __forceinline__ void compute_chunk(int c) {
        const int xb = c * WX;
        const char* ab = sb + lo * LSTR + 16 * hi;
        // transposed D: lane lo = output ROW, (4*hi + reg) = output COL
        float* ob = out + (size_t)(y0 + lo) * OUT_N + xb + 4 * hi;
        __builtin_amdgcn_s_setprio(1);
        #pragma unroll
        for (int t8 = 0; t8 < 7; ++t8) {
            f32x4 accA = { bv, bv, bv, bv };
            f32x4 accB = { 0.f, 0.f, 0.f, 0.f };
            bf16x8 a0 = *(const bf16x8*)(ab + 0*LSTR + 32*t8);
            bf16x8 a1 = *(const bf16x8*)(ab + 1*LSTR + 32*t8);
            bf16x8 a2 = *(const bf16x8*)(ab + 2*LSTR + 32*t8);
            bf16x8 a3 = *(const bf16x8*)(ab + 3*LSTR + 32*t8);
            bf16x8 a4 = *(const bf16x8*)(ab + 4*LSTR + 32*t8);
            bf16x8 a5 = *(const bf16x8*)(ab + 5*LSTR + 32*t8);
            bf16x8 a6 = *(const bf16x8*)(ab + 6*LSTR + 32*t8);
            // swapped operands: A = Toeplitz^T (constant), B = X-slab.
            // Fragments are expression-identical to the untransposed version;
            // shared (lane,e)->k convention makes HW k-permutations cancel.
            accA = __builtin_amdgcn_mfma_f32_16x16x32_bf16(bfrag[0], a0, accA, 0, 0, 0);
            accB = __builtin_amdgcn_mfma_f32_16x16x32_bf16(bfrag[1], a1, accB, 0, 0, 0);
            accA = __builtin_amdgcn_mfma_f32_16x16x32_bf16(bfrag[2], a2, accA, 0, 0, 0);
            accB = __builtin_amdgcn_mfma_f32_16x16x32_bf16(bfrag[3], a3, accB, 0, 0, 0);
            accA = __builtin_amdgcn_mfma_f32_16x16x32_bf16(bfrag[4], a4, accA, 0, 0, 0);
            accB = __builtin_amdgcn_mfma_f32_16x16x32_bf16(bfrag[5], a5, accB, 0, 0, 0);
            accA = __builtin_amdgcn_mfma_f32_16x16x32_bf16(bfrag[6], a6, accA, 0, 0, 0);
            D2 acc; acc.v = accA + accB;

            if constexpr (!G) {
                double* po = (double*)(ob + 16 * t8);       // col even -> 8B aligned
                po[0] = acc.d[0];
                po[1] = acc.d[1];
            } else {
                const int oy = y0 + lo;
                const int ox = xb + 16 * t8 + 4 * hi;
                if (oy < OUT_N) {
                    #pragma unroll
                    for (int r = 0; r < 4; ++r)
                        if (ox + r < OUT_N) ob[(size_t)16 * t8 + r] = acc.v[r];
                }
            }
        }
        __builtin_amdgcn_s_setprio(0);
    }

    __device__ __forceinline__ void run(int c0, int c1) {
        if (c0 >= c1) return;
        load_chunk(c0);
        write_chunk();
        asm volatile("s_waitcnt lgkmcnt(0)" ::: "memory");
        __builtin_amdgcn_sched_barrier(0);

        for (int c = c0; c < c1; ++c) {
            const bool pre = (c + 1 < c1);
            if (pre) load_chunk(c + 1);          // HBM latency hides under compute
            __builtin_amdgcn_sched_barrier(0);
            compute_chunk(c);
            __builtin_amdgcn_sched_barrier(0);
            if (pre) {
                asm volatile("s_waitcnt lgkmcnt(0)" ::: "memory"); // ds_reads retired (WAR)
                write_chunk();
                asm volatile("s_waitcnt lgkmcnt(0)" ::: "memory"); // writes visible to own reads
                __builtin_amdgcn_sched_barrier(0);
            }
        }
    }
};

__global__ __launch_bounds__(256, 4)
void conv7x7_t(const float* __restrict__ X, const float* __restrict__ Kw,
               const float* __restrict__ bias, float* __restrict__ out) {
    __shared__ __align__(16) char sb_all[4 * WAVE_LDS];   // 23936 B -> 6 blocks/CU

    const int tid  = threadIdx.x;
    const int lane = tid & 63;
    const int wv   = tid >> 6;

    // bijective XCD swizzle (1536 % 8 == 0): 192 contiguous work items per XCD
    const int bid  = blockIdx.x;
    const int swz  = (bid & 7) * (NBLK / 8) + (bid >> 3);
    const int grp  = swz / NPANEL;
    const int pan  = swz - grp * NPANEL;
    const int band = grp * 4 + wv;            // 0..511

    const int c0 = (NCHT * pan) / NPANEL;     // 6-7 chunks per wave, exact cover
    const int c1 = (NCHT * (pan + 1)) / NPANEL;

    const int lo = lane & 15, hi = lane >> 4;
    // Toeplitz fragment: value w[ky][8*hi+e-lo] (same expression for A- or B-slot)
    bf16x8 bfrag[KS];
    #pragma unroll
    for (int ky = 0; ky < KS; ++ky) {
        bf16x8 bvv;
        #pragma unroll
        for (int e = 0; e < 8; ++e) {
            const int d = 8 * hi + e - lo;
            bvv[e] = (__bf16)((d >= 0 && d < KS) ? Kw[ky * KS + d] : 0.0f);
        }
        bfrag[ky] = bvv;
    }

    if (band < 511) {
        WavePipe<false> p;
        p.X = X; p.out = out; p.sb = sb_all + wv * WAVE_LDS;
        p.y0 = band * 16; p.lo = lo; p.hi = hi;
        p.ls5 = lane >> 5; p.l31 = lane & 31; p.bv = bias[0];
        #pragma unroll
        for (int k = 0; k < KS; ++k) p.bfrag[k] = bfrag[k];
        p.run(c0, min(c1, GCH));
        if (c1 > GCH) {                        // guarded final chunk (cols 8176..8185)
            WavePipe<true> q;
            q.X = X; q.out = out; q.sb = sb_all + wv * WAVE_LDS;
            q.y0 = band * 16; q.lo = lo; q.hi = hi;
            q.ls5 = lane >> 5; q.l31 = lane & 31; q.bv = bias[0];
            #pragma unroll
            for (int k = 0; k < KS; ++k) q.bfrag[k] = bfrag[k];
            q.run(GCH, NCHT);
        }
    } else {
        WavePipe<true> p;                      // bottom band: rows guarded throughout
        p.X = X; p.out = out; p.sb = sb_all + wv * WAVE_LDS;
        p.y0 = band * 16; p.lo = lo; p.hi = hi;
        p.ls5 = lane >> 5; p.l31 = lane & 31; p.bv = bias[0];
        #pragma unroll
        for (int k = 0; k < KS; ++k) p.bfrag[k] = bfrag[k];
        p.run(c0, c1);
    }
}

extern "C" void kernel_launch(void* const* d_in, const int* in_sizes, int n_in,
                              void* d_out, int out_size, void* d_ws, size_t ws_size,
                              hipStream_t stream) {
    const float* X    = (const float*)d_in[0];
    const float* Kw   = (const float*)d_in[1];
    const float* bias = (const float*)d_in[2];
    float* out = (float*)d_out;

    conv7x7_t<<<dim3(NBLK), dim3(256), 0, stream>>>(X, Kw, bias, out);
}

// Round 8
// 141.464 us; speedup vs baseline: 1.1055x; 1.1055x over previous
//
#include <hip/hip_runtime.h>
#include <hip/hip_bf16.h>

#define IN_N    8192
#define OUT_N   8186
#define KS      7

#define SCOLS   512            // staged fp32 cols per strip (2 KB per row burst)
#define OCOLS   496            // output cols per strip
#define NSTRIP  17             // 16 full strips + 1 partial (cols 7936..8185)
#define NSEG    45             // vertical segments
#define NBLK    (NSTRIP * NSEG) // 765 blocks ~= 3/CU
#define NROWB   40             // circular buffer depth (rows)
#define LSTR    1040           // LDS bytes/row: 512*2 + 16 pad
#define NT8     31             // 16-col output tiles per strip
#define TOTSTEP 512            // 16-row steps covering all output rows

typedef __bf16 bf16x8 __attribute__((ext_vector_type(8)));
typedef float  f32x4  __attribute__((ext_vector_type(4)));

union BFU { __bf16 h; unsigned short u; };
__device__ __forceinline__ unsigned short f2bf(float f) {
    BFU c; c.h = (__bf16)f; return c.u;
}

template<bool G>
__device__ __forceinline__ void run_strip(
    const float* __restrict__ X, float* __restrict__ out,
    char* sb, const bf16x8* bfrag, float bv,
    int X0, int s0, int s1, int tid)
{
    const int lane = tid & 63;
    const int wv   = tid >> 6;
    const int lo   = lane & 15;
    const int hi   = lane >> 4;
    const int p    = tid >> 7;            // row parity for staging
    const int cg   = tid & 127;           // granule col 0..127
    const int ccol = X0 + 4 * cg;         // fp32 col of this thread's granule
    const int wcol = cg * 8;              // LDS byte col (4 bf16)

    // write-slot base for rows (16s + 22 + 2k + p); advanced by 16 mod 40 per step
    int wbase = (16 * s0 + 22 + p) % NROWB;

    // fragment read byte-offsets for rows (16s + lo + ky) mod 40
    int roff[KS];
    #pragma unroll
    for (int ky = 0; ky < KS; ++ky)
        roff[ky] = ((16 * s0 + lo + ky) % NROWB) * LSTR + 16 * hi;

    // ---- prologue: stage rows 16*s0 .. 16*s0+21 (11 rounds, 2816 granules) ----
    #pragma unroll
    for (int k = 0; k < 11; ++k) {
        int r = 16 * s0 + 2 * k + p;
        int c = ccol;
        if (G) { r = min(r, IN_N - 1); c = min(c, IN_N - 4); } // clamped junk only feeds guarded-out outputs
        float4 v = *(const float4*)(X + (size_t)r * IN_N + c);
        ushort4 h;
        h.x = f2bf(v.x); h.y = f2bf(v.y); h.z = f2bf(v.z); h.w = f2bf(v.w);
        const int slot = (16 * s0 + 2 * k + p) % NROWB;
        *(ushort4*)(sb + slot * LSTR + wcol) = h;
    }
    asm volatile("s_waitcnt lgkmcnt(0)" ::: "memory");
    __builtin_amdgcn_s_barrier();
    __builtin_amdgcn_sched_barrier(0);

    float4 ld[8];
    for (int s = s0; s < s1; ++s) {
        const int Y = 16 * s;
        const bool pre = (s + 1 < s1);

        // issue next 16 rows EARLY (1 KB contiguous per wave-load; latency hides under MFMA)
        if (pre) {
            #pragma unroll
            for (int k = 0; k < 8; ++k) {
                int r = Y + 22 + 2 * k + p;
                int c = ccol;
                if (G) { r = min(r, IN_N - 1); c = min(c, IN_N - 4); }
                ld[k] = *(const float4*)(X + (size_t)r * IN_N + c);
            }
        }
        __builtin_amdgcn_sched_barrier(0);

        // compute: tiles wv, wv+4, ... (31 tiles across 4 waves)
        for (int t8 = wv; t8 < NT8; t8 += 4) {
            const int off = 32 * t8;
            f32x4 accA = { bv, bv, bv, bv };
            f32x4 accB = { 0.f, 0.f, 0.f, 0.f };
            bf16x8 a0 = *(const bf16x8*)(sb + roff[0] + off);
            bf16x8 a1 = *(const bf16x8*)(sb + roff[1] + off);
            bf16x8 a2 = *(const bf16x8*)(sb + roff[2] + off);
            bf16x8 a3 = *(const bf16x8*)(sb + roff[3] + off);
            bf16x8 a4 = *(const bf16x8*)(sb + roff[4] + off);
            bf16x8 a5 = *(const bf16x8*)(sb + roff[5] + off);
            bf16x8 a6 = *(const bf16x8*)(sb + roff[6] + off);
            // swapped operands (A = Toeplitz^T); shared (lane,e)->k convention cancels HW k-permutation
            accA = __builtin_amdgcn_mfma_f32_16x16x32_bf16(bfrag[0], a0, accA, 0, 0, 0);
            accB = __builtin_amdgcn_mfma_f32_16x16x32_bf16(bfrag[1], a1, accB, 0, 0, 0);
            accA = __builtin_amdgcn_mfma_f32_16x16x32_bf16(bfrag[2], a2, accA, 0, 0, 0);
            accB = __builtin_amdgcn_mfma_f32_16x16x32_bf16(bfrag[3], a3, accB, 0, 0, 0);
            accA = __builtin_amdgcn_mfma_f32_16x16x32_bf16(bfrag[4], a4, accA, 0, 0, 0);
            accB = __builtin_amdgcn_mfma_f32_16x16x32_bf16(bfrag[5], a5, accB, 0, 0, 0);
            accA = __builtin_amdgcn_mfma_f32_16x16x32_bf16(bfrag[6], a6, accA, 0, 0, 0);
            const f32x4 acc = accA + accB;

            const int oy = Y + lo;                  // transposed D: lane lo = out row
            const int ox = X0 + 16 * t8 + 4 * hi;   // 4hi+reg = out col (even -> 8B aligned)
            if constexpr (!G) {
                float2* po = (float2*)(out + (size_t)oy * OUT_N + ox);
                po[0] = make_float2(acc[0], acc[1]);
                po[1] = make_float2(acc[2], acc[3]);
            } else {
                if (oy < OUT_N) {
                    #pragma unroll
                    for (int r = 0; r < 4; ++r)
                        if (ox + r < OUT_N) out[(size_t)oy * OUT_N + ox + r] = acc[r];
                }
            }
        }
        __builtin_amdgcn_sched_barrier(0);

        // convert + ds_write rows Y+22..Y+37 (slots disjoint from this step's read slots mod 40)
        if (pre) {
            #pragma unroll
            for (int k = 0; k < 8; ++k) {
                ushort4 h;
                h.x = f2bf(ld[k].x); h.y = f2bf(ld[k].y);
                h.z = f2bf(ld[k].z); h.w = f2bf(ld[k].w);
                int slot = wbase + 2 * k;
                if (slot >= NROWB) slot -= NROWB;
                *(ushort4*)(sb + slot * LSTR + wcol) = h;
            }
            asm volatile("s_waitcnt lgkmcnt(0)" ::: "memory");  // writes visible
            __builtin_amdgcn_s_barrier();                        // one barrier per step
            __builtin_amdgcn_sched_barrier(0);
        }

        // advance circular indices
        wbase += 16; if (wbase >= NROWB) wbase -= NROWB;
        #pragma unroll
        for (int ky = 0; ky < KS; ++ky) {
            roff[ky] += 16 * LSTR;
            if (roff[ky] >= NROWB * LSTR) roff[ky] -= NROWB * LSTR;
        }
    }
}

__global__ __launch_bounds__(256, 3)
void conv7x7_roll(const float* __restrict__ X, const float* __restrict__ Kw,
                  const float* __restrict__ bias, float* __restrict__ out) {
    __shared__ __align__(16) char sb[NROWB * LSTR];   // 41600 B -> 3 blocks/CU

    const int tid  = threadIdx.x;
    const int lane = tid & 63;
    const int lo   = lane & 15;
    const int hi   = lane >> 4;

    // bijective XCD swizzle for nwg=765 (q=95, r=5): contiguous wg band per XCD
    const int orig = blockIdx.x;
    const int xcd  = orig & 7;
    const int idx  = orig >> 3;
    const int wg   = (xcd < 5 ? xcd * 96 : 5 * 96 + (xcd - 5) * 95) + idx;
    const int seg   = wg / NSTRIP;     // seg-major: neighbors share the input row band
    const int strip = wg - seg * NSTRIP;

    const int X0 = strip * OCOLS;
    const int s0 = (TOTSTEP * seg) / NSEG;
    const int s1 = (TOTSTEP * (seg + 1)) / NSEG;

    // Toeplitz fragment: value w[ky][8*hi+e-lo] (identical expression for A- or B-slot)
    bf16x8 bfrag[KS];
    #pragma unroll
    for (int ky = 0; ky < KS; ++ky) {
        bf16x8 bv;
        #pragma unroll
        for (int e = 0; e < 8; ++e) {
            const int d = 8 * hi + e - lo;
            bv[e] = (__bf16)((d >= 0 && d < KS) ? Kw[ky * KS + d] : 0.0f);
        }
        bfrag[ky] = bv;
    }
    const float b = bias[0];

    if (strip < NSTRIP - 1 && seg < NSEG - 1)
        run_strip<false>(X, out, sb, bfrag, b, X0, s0, s1, tid);
    else
        run_strip<true >(X, out, sb, bfrag, b, X0, s0, s1, tid);
}

extern "C" void kernel_launch(void* const* d_in, const int* in_sizes, int n_in,
                              void* d_out, int out_size, void* d_ws, size_t ws_size,
                              hipStream_t stream) {
    const float* X    = (const float*)d_in[0];
    const float* Kw   = (const float*)d_in[1];
    const float* bias = (const float*)d_in[2];
    float* out = (float*)d_out;

    conv7x7_roll<<<dim3(NBLK), dim3(256), 0, stream>>>(X, Kw, bias, out);
}